// Round 10
// baseline (222.592 us; speedup 1.0000x reference)
//
#include <hip/hip_runtime.h>
#include <hip/hip_bf16.h>
#include <cstdint>
#include <cstddef>

typedef __attribute__((ext_vector_type(8))) _Float16 half8;
typedef __attribute__((ext_vector_type(4))) float f32x4;
typedef __attribute__((ext_vector_type(8))) unsigned short ushort8v;
typedef __attribute__((ext_vector_type(4))) unsigned short ushort4v;

__device__ __forceinline__ unsigned short f2h_bits(float x) {
  _Float16 h = (_Float16)x;
  union { _Float16 h; unsigned short u; } cv; cv.h = h; return cv.u;
}

__device__ __forceinline__ void barrier_raw() {
  asm volatile("" ::: "memory");
  __builtin_amdgcn_s_barrier();
  asm volatile("" ::: "memory");
}
template<int N> __device__ __forceinline__ void vmw() {
  static_assert(N == 0 || N == 3 || N == 4 || N == 8 || N == 16 || N == 24, "unsupported vmcnt");
  if constexpr (N == 0)  asm volatile("s_waitcnt vmcnt(0)" ::: "memory");
  if constexpr (N == 3)  asm volatile("s_waitcnt vmcnt(3)" ::: "memory");
  if constexpr (N == 4)  asm volatile("s_waitcnt vmcnt(4)" ::: "memory");
  if constexpr (N == 8)  asm volatile("s_waitcnt vmcnt(8)" ::: "memory");
  if constexpr (N == 16) asm volatile("s_waitcnt vmcnt(16)" ::: "memory");
  if constexpr (N == 24) asm volatile("s_waitcnt vmcnt(24)" ::: "memory");
}
__device__ __forceinline__ void lgkm0() {
  asm volatile("s_waitcnt lgkmcnt(0)" ::: "memory");
}

// pinned 16B global load: compiler cannot sink/merge it; WE own the waitcnt.
__device__ __forceinline__ half8 gload16(const unsigned short* p) {
  half8 r;
  asm volatile("global_load_dwordx4 %0, %1, off" : "=v"(r) : "v"(p));
  return r;
}

// ---------------- prep kernels ----------------

__global__ __launch_bounds__(256) void k_f32_to_f16(const float* __restrict__ src,
                                                    unsigned short* __restrict__ dst, int n4) {
  int i = blockIdx.x * 256 + threadIdx.x;
  if (i >= n4) return;
  float4 v = ((const float4*)src)[i];
  ushort4v o;
  o[0] = f2h_bits(v.x); o[1] = f2h_bits(v.y); o[2] = f2h_bits(v.z); o[3] = f2h_bits(v.w);
  ((ushort4v*)dst)[i] = o;
}

__global__ __launch_bounds__(256) void k_transpose_f16(const float* __restrict__ W,
                                                       unsigned short* __restrict__ Wt,
                                                       int Kd, int N) {
  int tid = blockIdx.x * 256 + threadIdx.x;
  int total = (Kd >> 3) * N;
  if (tid >= total) return;
  int kc = tid / N;
  int n  = tid - kc * N;
  int k0 = kc << 3;
  ushort8v o;
#pragma unroll
  for (int j = 0; j < 8; ++j) o[j] = f2h_bits(W[(size_t)(k0 + j) * N + n]);
  *(ushort8v*)(&Wt[(size_t)n * Kd + k0]) = o;
}

// Build head weight PRE-SHUFFLED into MFMA fragment order + bias bhd.
// Rows r: 0..127 mu; 128..2175 tril unpacked (k*256+i*16+j, zero row if j>i);
// 2176..2183 pi; 2184..2239 pad. B'[strip][t][n][lane][8].
__global__ __launch_bounds__(256) void k_build_head(
    const float* __restrict__ Wmu, const float* __restrict__ Wt,
    const float* __restrict__ Wpi,
    const float* __restrict__ bmu, const float* __restrict__ bt,
    const float* __restrict__ bpi,
    unsigned short* __restrict__ bsh, float* __restrict__ bhd)
{
  int tid = blockIdx.x * 256 + threadIdx.x;   // (r, octet): 2240*64
  if (tid >= 2240 * 64) return;
  int r  = tid >> 6;
  int o  = tid & 63;
  int d0 = o << 3;

  const float* src = nullptr; int stride = 0;
  if (r < 128) { src = Wmu + r; stride = 128; }
  else if (r < 2176) {
    int rU = r - 128, k = rU >> 8, i = (rU >> 4) & 15, j = rU & 15;
    if (j <= i) { src = Wt + k * 136 + ((i * (i + 1)) >> 1) + j; stride = 1088; }
  } else if (r < 2184) { src = Wpi + (r - 2176); stride = 8; }

  ushort8v ov;
#pragma unroll
  for (int jj = 0; jj < 8; ++jj)
    ov[jj] = src ? f2h_bits(src[(size_t)(d0 + jj) * stride]) : (unsigned short)0;

  const int strip = r >> 6;
  const int n     = (r >> 4) & 3;
  const int l15   = r & 15;
  const int t     = o >> 2;
  const int lk    = o & 3;
  const int lane  = (lk << 4) | l15;
  const size_t off = ((((size_t)(strip * 16 + t) * 4 + n) * 64) + lane) * 8;
  *(ushort8v*)(&bsh[off]) = ov;

  if (o == 0) {
    float b = 0.f;
    if (r < 128) b = bmu[r];
    else if (r < 2176) {
      int rU = r - 128, k = rU >> 8, i = (rU >> 4) & 15, j = rU & 15;
      if (j <= i) b = bt[k * 136 + ((i * (i + 1)) >> 1) + j];
    } else if (r < 2184) b = bpi[r - 2176];
    bhd[r] = b;
  }
}

// ---- shared epilogue helpers (swapped-operand layout: row=l15-side, col=lk*4+reg) ----

__device__ __forceinline__ void epi_relu_h(const f32x4& a, const float* bias, int col0,
                                           unsigned short* Hout, size_t row, int N) {
  float4 b4 = *(const float4*)&bias[col0];
  ushort4v o;
  float v0 = a[0] + b4.x; o[0] = f2h_bits(v0 > 0.f ? v0 : 0.f);
  float v1 = a[1] + b4.y; o[1] = f2h_bits(v1 > 0.f ? v1 : 0.f);
  float v2 = a[2] + b4.z; o[2] = f2h_bits(v2 > 0.f ? v2 : 0.f);
  float v3 = a[3] + b4.w; o[3] = f2h_bits(v3 > 0.f ? v3 : 0.f);
  *(ushort4v*)&Hout[row * N + col0] = o;
}

__device__ __forceinline__ void epi_head(const f32x4& a, const float* bias, int col0,
                                         size_t row, float* out_pi, float* out_mu,
                                         float* out_tril) {
  if (col0 >= 2184) return;   // pad
  float4 b4 = *(const float4*)&bias[col0];
  float v[4] = { a[0] + b4.x, a[1] + b4.y, a[2] + b4.z, a[3] + b4.w };
  if (col0 < 128) {
    *(float4*)&out_mu[row * 128 + col0] = make_float4(v[0], v[1], v[2], v[3]);
  } else if (col0 < 2176) {
    const int cc0 = col0 - 128;
    const int i   = (cc0 >> 4) & 15;
    const int j0  = cc0 & 15;
#pragma unroll
    for (int r = 0; r < 4; ++r) if (j0 + r == i) v[r] = expf(v[r]);
    *(float4*)&out_tril[row * 2048 + cc0] = make_float4(v[0], v[1], v[2], v[3]);
  } else {
    // pi: lanes lk=0 hold cols 2176-79, lk=1 hold 2180-83 for the same row (lane^16)
    float m4 = fmaxf(fmaxf(v[0], v[1]), fmaxf(v[2], v[3]));
    float mx = fmaxf(m4, __shfl_xor(m4, 16));
    float e[4], s4 = 0.f;
#pragma unroll
    for (int r = 0; r < 4; ++r) { e[r] = expf(v[r] - mx); s4 += e[r]; }
    float sm = s4 + __shfl_xor(s4, 16);
    *(float4*)&out_pi[row * 8 + (col0 - 2176)] =
        make_float4(e[0] / sm, e[1] / sm, e[2] / sm, e[3] / sm);
  }
}

// ---- flatmm head v4: depth-3 named pipeline + amdgpu_waves_per_eu(2,2) ----
// The (2,2) pin gives the register allocator a 256-VGPR budget so all 4 fragment
// sets stay in registers (no spill -> no hidden compiler waitcnt killing the
// pipeline). Steady-state vmcnt(24): tiles t+1..t+3 (24 loads) stay in flight.

__global__ __launch_bounds__(256)
__attribute__((amdgpu_waves_per_eu(2, 2)))
void k_flat_head(
    const unsigned short* __restrict__ A,    // h2 [16384][512] fp16 row-major
    const unsigned short* __restrict__ Bs,   // shuffled [35][16][4][64][8]
    const float* __restrict__ bias,
    float* __restrict__ out_pi,
    float* __restrict__ out_mu,
    float* __restrict__ out_tril)
{
  constexpr int NK = 16;
  const int tid  = threadIdx.x;
  const int lane = tid & 63;
  const int wv   = tid >> 6;
  const int l15  = lane & 15;
  const int lk   = lane >> 4;

  constexpr int nStrip = 35;
  const int cpx = gridDim.x >> 3;
  const int bid = blockIdx.x;
  const int swz = (bid & 7) * cpx + (bid >> 3);   // 2240 % 8 == 0: bijective
  const int bmi   = swz / nStrip;
  const int strip = swz % nStrip;                 // strip-minor: A-panel XCD-L2-resident
  const int row0  = bmi * 256 + wv * 64;

  const unsigned short* aP = A  + (size_t)(row0 + l15) * 512 + lk * 8;
  const unsigned short* a0 = aP;
  const unsigned short* a1 = aP + (size_t)16 * 512;
  const unsigned short* a2 = aP + (size_t)32 * 512;
  const unsigned short* a3 = aP + (size_t)48 * 512;
  const unsigned short* bP = Bs + ((size_t)strip * NK * 4 * 64 + (size_t)lane) * 8;

  f32x4 acc[4][4] = {};   // constant-indexed only (SROA-safe)

  // 32 NAMED fragment registers (4 sets x (4 A-frag + 4 B-frag)).
  half8 aA0, aA1, aA2, aA3, bA0, bA1, bA2, bA3;
  half8 aB0, aB1, aB2, aB3, bB0, bB1, bB2, bB3;
  half8 aC0, aC1, aC2, aC3, bC0, bC1, bC2, bC3;
  half8 aD0, aD1, aD2, aD3, bD0, bD1, bD2, bD3;

#define ISSUE(S, t) do {                                        \
    a##S##0 = gload16(a0 + (t) * 32);                           \
    a##S##1 = gload16(a1 + (t) * 32);                           \
    a##S##2 = gload16(a2 + (t) * 32);                           \
    a##S##3 = gload16(a3 + (t) * 32);                           \
    const unsigned short* bt_ = bP + (size_t)(t) * 2048;        \
    b##S##0 = gload16(bt_);                                     \
    b##S##1 = gload16(bt_ + 512);                               \
    b##S##2 = gload16(bt_ + 1024);                              \
    b##S##3 = gload16(bt_ + 1536);                              \
  } while (0)

#define STEPX(S) do {                                                                     \
    __builtin_amdgcn_s_setprio(1);                                                        \
    acc[0][0] = __builtin_amdgcn_mfma_f32_16x16x32_f16(b##S##0, a##S##0, acc[0][0],0,0,0); \
    acc[0][1] = __builtin_amdgcn_mfma_f32_16x16x32_f16(b##S##1, a##S##0, acc[0][1],0,0,0); \
    acc[0][2] = __builtin_amdgcn_mfma_f32_16x16x32_f16(b##S##2, a##S##0, acc[0][2],0,0,0); \
    acc[0][3] = __builtin_amdgcn_mfma_f32_16x16x32_f16(b##S##3, a##S##0, acc[0][3],0,0,0); \
    acc[1][0] = __builtin_amdgcn_mfma_f32_16x16x32_f16(b##S##0, a##S##1, acc[1][0],0,0,0); \
    acc[1][1] = __builtin_amdgcn_mfma_f32_16x16x32_f16(b##S##1, a##S##1, acc[1][1],0,0,0); \
    acc[1][2] = __builtin_amdgcn_mfma_f32_16x16x32_f16(b##S##2, a##S##1, acc[1][2],0,0,0); \
    acc[1][3] = __builtin_amdgcn_mfma_f32_16x16x32_f16(b##S##3, a##S##1, acc[1][3],0,0,0); \
    acc[2][0] = __builtin_amdgcn_mfma_f32_16x16x32_f16(b##S##0, a##S##2, acc[2][0],0,0,0); \
    acc[2][1] = __builtin_amdgcn_mfma_f32_16x16x32_f16(b##S##1, a##S##2, acc[2][1],0,0,0); \
    acc[2][2] = __builtin_amdgcn_mfma_f32_16x16x32_f16(b##S##2, a##S##2, acc[2][2],0,0,0); \
    acc[2][3] = __builtin_amdgcn_mfma_f32_16x16x32_f16(b##S##3, a##S##2, acc[2][3],0,0,0); \
    acc[3][0] = __builtin_amdgcn_mfma_f32_16x16x32_f16(b##S##0, a##S##3, acc[3][0],0,0,0); \
    acc[3][1] = __builtin_amdgcn_mfma_f32_16x16x32_f16(b##S##1, a##S##3, acc[3][1],0,0,0); \
    acc[3][2] = __builtin_amdgcn_mfma_f32_16x16x32_f16(b##S##2, a##S##3, acc[3][2],0,0,0); \
    acc[3][3] = __builtin_amdgcn_mfma_f32_16x16x32_f16(b##S##3, a##S##3, acc[3][3],0,0,0); \
    __builtin_amdgcn_s_setprio(0);                                                        \
    __builtin_amdgcn_sched_barrier(0);                                                    \
  } while (0)

#define W24 do { vmw<24>(); __builtin_amdgcn_sched_barrier(0); } while (0)
#define W16 do { vmw<16>(); __builtin_amdgcn_sched_barrier(0); } while (0)
#define W8  do { vmw<8>();  __builtin_amdgcn_sched_barrier(0); } while (0)
#define W0  do { vmw<0>();  __builtin_amdgcn_sched_barrier(0); } while (0)

  // Ledger: 8 loads/tile, 4 sets rotating A,B,C,D (tile t -> set t%4).
  // After each ISSUE, 32 outstanding; W24 retires exactly the oldest tile.
  ISSUE(A, 0); ISSUE(B, 1); ISSUE(C, 2);
  ISSUE(D, 3);  W24; STEPX(A);   // t=0
  ISSUE(A, 4);  W24; STEPX(B);   // t=1
  ISSUE(B, 5);  W24; STEPX(C);   // t=2
  ISSUE(C, 6);  W24; STEPX(D);   // t=3
  ISSUE(D, 7);  W24; STEPX(A);   // t=4
  ISSUE(A, 8);  W24; STEPX(B);   // t=5
  ISSUE(B, 9);  W24; STEPX(C);   // t=6
  ISSUE(C, 10); W24; STEPX(D);   // t=7
  ISSUE(D, 11); W24; STEPX(A);   // t=8
  ISSUE(A, 12); W24; STEPX(B);   // t=9
  ISSUE(B, 13); W24; STEPX(C);   // t=10
  ISSUE(C, 14); W24; STEPX(D);   // t=11
  ISSUE(D, 15); W24; STEPX(A);   // t=12
  W16; STEPX(B);                 // t=13
  W8;  STEPX(C);                 // t=14
  W0;  STEPX(D);                 // t=15
#undef ISSUE
#undef STEPX
#undef W24
#undef W16
#undef W8
#undef W0

  // epilogue: row = row0 + m*16 + l15 ; col0 = strip*64 + n*16 + lk*4
#pragma unroll
  for (int m = 0; m < 4; ++m) {
    const size_t row = row0 + (m << 4) + l15;
#pragma unroll
    for (int n = 0; n < 4; ++n) {
      const int col0 = strip * 64 + (n << 4) + (lk << 2);
      epi_head(acc[m][n], bias, col0, row, out_pi, out_mu, out_tril);
    }
  }
}

// -------- 3-buffer counted-vmcnt 128x128 GEMM (round-6, verified) — L0 --------

template<int EPI>
__global__ __launch_bounds__(256) void k_gemm3b(
    const unsigned short* __restrict__ A,
    const unsigned short* __restrict__ Bt,
    int Kd, int N, int nNb,
    const float* __restrict__ bias,
    unsigned short* __restrict__ Hout,
    float* __restrict__ out_pi,
    float* __restrict__ out_mu,
    float* __restrict__ out_tril)
{
  __shared__ unsigned short Ald[3][128 * 32];
  __shared__ unsigned short Bld[3][128 * 32];

  const int tid  = threadIdx.x;
  const int lane = tid & 63;
  const int wv   = tid >> 6;
  const int wr   = wv >> 1;
  const int wc   = wv & 1;
  const int l15  = lane & 15;
  const int lk   = lane >> 4;

  const int cpx = gridDim.x >> 3;
  const int bid = blockIdx.x;
  const int swz = (bid & 7) * cpx + (bid >> 3);
  const int bm  = (swz / nNb) << 7;
  const int bn  = (swz % nNb) << 7;

  f32x4 acc[4][4] = {};

  const unsigned short* aBase = A  + (size_t)bm * Kd;
  const unsigned short* bBase = Bt + (size_t)bn * Kd;

  const int xo = ((lk ^ ((l15 >> 1) & 3)) << 3);

  auto stage = [&](int bb, int kt) {
    const int k0 = kt << 5;
#pragma unroll
    for (int i = 0; i < 2; ++i) {
      const int cbase = (wv << 6) + (i << 8);
      const int c_    = cbase + lane;
      const int row   = c_ >> 2;
      const int sc    = (((c_ & 3) ^ ((c_ >> 3) & 3)) << 3);
      __builtin_amdgcn_global_load_lds(
          (const __attribute__((address_space(1))) void*)(aBase + (size_t)row * Kd + k0 + sc),
          (__attribute__((address_space(3))) void*)(&Ald[bb][cbase << 3]),
          16, 0, 0);
      __builtin_amdgcn_global_load_lds(
          (const __attribute__((address_space(1))) void*)(bBase + (size_t)row * Kd + k0 + sc),
          (__attribute__((address_space(3))) void*)(&Bld[bb][cbase << 3]),
          16, 0, 0);
    }
  };

  const int nk = Kd >> 5;
  stage(0, 0);
  stage(1, 1);
  vmw<4>();
  barrier_raw();

  int i0 = 0, i1 = 1, i2 = 2;
  for (int kt = 0; kt < nk; ++kt) {
    if (kt + 2 < nk) stage(i2, kt + 2);

    half8 af[4], bfr[4];
#pragma unroll
    for (int m = 0; m < 4; ++m)
      af[m]  = *(const half8*)&Ald[i0][((wr << 6) + (m << 4) + l15) * 32 + xo];
#pragma unroll
    for (int n = 0; n < 4; ++n)
      bfr[n] = *(const half8*)&Bld[i0][((wc << 6) + (n << 4) + l15) * 32 + xo];

    __builtin_amdgcn_s_setprio(1);
#pragma unroll
    for (int m = 0; m < 4; ++m)
#pragma unroll
      for (int n = 0; n < 4; ++n)
        acc[m][n] = __builtin_amdgcn_mfma_f32_16x16x32_f16(bfr[n], af[m], acc[m][n], 0, 0, 0);
    __builtin_amdgcn_s_setprio(0);

    if (kt + 1 < nk) {
      if (kt + 2 < nk) vmw<4>();
      else             vmw<0>();
      barrier_raw();
    }
    const int t = i0; i0 = i1; i1 = i2; i2 = t;
  }

#pragma unroll
  for (int m = 0; m < 4; ++m) {
    const size_t row = bm + (wr << 6) + (m << 4) + l15;
#pragma unroll
    for (int n = 0; n < 4; ++n) {
      const int col0 = bn + (wc << 6) + (n << 4) + (lk << 2);
      if (EPI == 0) epi_relu_h(acc[m][n], bias, col0, Hout, row, N);
      else          epi_head(acc[m][n], bias, col0, row, out_pi, out_mu, out_tril);
    }
  }
}

// -------- 8-phase counted-vmcnt GEMM (rounds 4-9 verified) — L1/L2 --------

template<int NH, int M_rep>
__device__ __forceinline__ void mfma_phase(const half8* af, const half8* bf,
                                           f32x4 (*acc)[4]) {
  __builtin_amdgcn_s_setprio(1);
#pragma unroll
  for (int m = 0; m < M_rep; ++m) {
    acc[m][NH * 2 + 0] = __builtin_amdgcn_mfma_f32_16x16x32_f16(bf[0], af[m], acc[m][NH * 2 + 0], 0, 0, 0);
    acc[m][NH * 2 + 1] = __builtin_amdgcn_mfma_f32_16x16x32_f16(bf[1], af[m], acc[m][NH * 2 + 1], 0, 0, 0);
  }
  __builtin_amdgcn_s_setprio(0);
}

template<int BM, int BN>
__global__ __launch_bounds__(512) void k_gemm8p(
    const unsigned short* __restrict__ A,
    const unsigned short* __restrict__ Bt,
    int Kd, int N, int nNb,
    const float* __restrict__ bias,
    unsigned short* __restrict__ Hout)
{
  constexpr int M_rep = BM / 32;
  constexpr int A_LD  = BM / 128;
  constexpr int B_LD  = BN / 128;
  constexpr int WN    = A_LD + B_LD;

  __shared__ unsigned short Ald[2][2][BM * 32];
  __shared__ unsigned short Bld[2][2][BN * 32];

  const int tid  = threadIdx.x;
  const int lane = tid & 63;
  const int wid  = tid >> 6;
  const int wm   = wid >> 2;
  const int wn   = wid & 3;
  const int l15  = lane & 15;
  const int lk   = lane >> 4;

  const int cpx = gridDim.x >> 3;
  const int bid = blockIdx.x;
  const int swz = (bid & 7) * cpx + (bid >> 3);
  const int bm  = (swz / nNb) * BM;
  const int bn  = (swz % nNb) * BN;

  const unsigned short* aBase = A  + (size_t)bm * Kd;
  const unsigned short* bBase = Bt + (size_t)bn * Kd;

  f32x4 acc[M_rep][4] = {};

  const int xo   = ((lk ^ ((l15 >> 1) & 3)) << 3);
  const int rowA = wm * (BM / 2) + l15;
  const int colB = wn * 64 + l15;

  auto stageA = [&](int bb, int h, int k0) {
#pragma unroll
    for (int i = 0; i < A_LD; ++i) {
      const int cbase = (wid << 6) + (i << 9);
      const int c_    = cbase + lane;
      const int row   = c_ >> 2;
      const int sc    = (((c_ & 3) ^ ((c_ >> 3) & 3)) << 3);
      __builtin_amdgcn_global_load_lds(
          (const __attribute__((address_space(1))) void*)(aBase + (size_t)row * Kd + k0 + h * 32 + sc),
          (__attribute__((address_space(3))) void*)(&Ald[bb][h][(size_t)cbase << 3]),
          16, 0, 0);
    }
  };
  auto stageB = [&](int bb, int h, int k0) {
#pragma unroll
    for (int i = 0; i < B_LD; ++i) {
      const int cbase = (wid << 6) + (i << 9);
      const int c_    = cbase + lane;
      const int row   = c_ >> 2;
      const int sc    = (((c_ & 3) ^ ((c_ >> 3) & 3)) << 3);
      __builtin_amdgcn_global_load_lds(
          (const __attribute__((address_space(1))) void*)(bBase + (size_t)row * Kd + k0 + h * 32 + sc),
          (__attribute__((address_space(3))) void*)(&Bld[bb][h][(size_t)cbase << 3]),
          16, 0, 0);
    }
  };

#define RD_A(kk)                                                                 \
  {                                                                              \
    _Pragma("unroll")                                                            \
    for (int m = 0; m < M_rep; ++m)                                              \
      af[m] = *(const half8*)&Ald[cur][kk][(size_t)(rowA + m * 16) * 32 + xo];   \
  }
#define RD_B(kk, nh)                                                             \
  {                                                                              \
    _Pragma("unroll")                                                            \
    for (int n2 = 0; n2 < 2; ++n2)                                               \
      bf[n2] = *(const half8*)&Bld[cur][kk][(size_t)(colB + ((nh) * 2 + n2) * 16) * 32 + xo]; \
  }

  const int nk = Kd >> 6;
  stageA(0, 0, 0); stageB(0, 0, 0); stageA(0, 1, 0); stageB(0, 1, 0);
  vmw<WN>();
  barrier_raw();

  int cur = 0;
  for (int kt = 0; kt < nk; ++kt) {
    const bool pre = (kt + 1 < nk);
    const int  k0n = (kt + 1) << 6;
    half8 af[M_rep], bf[2];

    RD_A(0); RD_B(0, 0);
    if (pre) stageA(cur ^ 1, 0, k0n);
    barrier_raw(); lgkm0();
    mfma_phase<0, M_rep>(af, bf, acc);
    barrier_raw();

    RD_B(0, 1);
    if (pre) stageB(cur ^ 1, 0, k0n);
    barrier_raw(); lgkm0();
    mfma_phase<1, M_rep>(af, bf, acc);
    if (pre) vmw<WN>(); else vmw<0>();
    barrier_raw();

    RD_A(1); RD_B(1, 0);
    if (pre) stageA(cur ^ 1, 1, k0n);
    barrier_raw(); lgkm0();
    mfma_phase<0, M_rep>(af, bf, acc);
    barrier_raw();

    RD_B(1, 1);
    if (pre) stageB(cur ^ 1, 1, k0n);
    barrier_raw(); lgkm0();
    mfma_phase<1, M_rep>(af, bf, acc);
    if (pre) vmw<WN>();
    barrier_raw();

    cur ^= 1;
  }
#undef RD_A
#undef RD_B

#pragma unroll
  for (int m = 0; m < M_rep; ++m) {
    const size_t row = bm + wm * (BM / 2) + (m << 4) + l15;
#pragma unroll
    for (int n = 0; n < 4; ++n) {
      const int col0 = bn + wn * 64 + (n << 4) + (lk << 2);
      epi_relu_h(acc[m][n], bias, col0, Hout, row, N);
    }
  }
}

// ---------------- launch ----------------

extern "C" void kernel_launch(void* const* d_in, const int* in_sizes, int n_in,
                              void* d_out, int out_size, void* d_ws, size_t ws_size,
                              hipStream_t stream)
{
  const float* x   = (const float*)d_in[0];
  const float* W0  = (const float*)d_in[1];
  const float* b0  = (const float*)d_in[2];
  const float* W1  = (const float*)d_in[3];
  const float* b1  = (const float*)d_in[4];
  const float* W2  = (const float*)d_in[5];
  const float* b2  = (const float*)d_in[6];
  const float* Wpi = (const float*)d_in[7];
  const float* bpi = (const float*)d_in[8];
  const float* Wmu = (const float*)d_in[9];
  const float* bmu = (const float*)d_in[10];
  const float* Wt  = (const float*)d_in[11];
  const float* bt  = (const float*)d_in[12];

  char* ws = (char*)d_ws;
  unsigned short* xh  = (unsigned short*)(ws);             //  8,388,608 B
  unsigned short* h0  = (unsigned short*)(ws + 8388608);   // 33,554,432 B
  unsigned short* h1  = (unsigned short*)(ws + 41943040);  // 33,554,432 B
  unsigned short* h2  = (unsigned short*)(ws + 8388608);   // 16,777,216 B (aliases h0 — dead by then)
  unsigned short* w0b = (unsigned short*)(ws + 75497472);  //    524,288 B [1024][256]
  unsigned short* w1b = (unsigned short*)(ws + 76021760);  //  2,097,152 B [1024][1024]
  unsigned short* w2b = (unsigned short*)(ws + 78118912);  //  1,048,576 B [512][1024]
  unsigned short* bsh = (unsigned short*)(ws + 79167488);  //  2,293,760 B shuffled head W
  float*          bhd = (float*)         (ws + 81526784);  //      9,216 B [2304]

  float* out_pi   = (float*)d_out;                // 131072
  float* out_mu   = (float*)d_out + 131072;       // 2097152
  float* out_tril = (float*)d_out + 2228224;      // 33554432

  // prep
  k_f32_to_f16<<<4096, 256, 0, stream>>>(x, xh, 1048576);
  k_transpose_f16<<<128, 256, 0, stream>>>(W0, w0b, 256, 1024);
  k_transpose_f16<<<512, 256, 0, stream>>>(W1, w1b, 1024, 1024);
  k_transpose_f16<<<256, 256, 0, stream>>>(W2, w2b, 1024, 512);
  k_build_head<<<560, 256, 0, stream>>>(Wmu, Wt, Wpi, bmu, bt, bpi, bsh, bhd);

  // L0: short-K (256) -> 3-buffer 128^2 counted-vmcnt, 1024 blocks
  k_gemm3b<0><<<1024, 256, 0, stream>>>(xh, w0b, 256, 1024, 8, b0, h0,
                                        nullptr, nullptr, nullptr);
  // L1/L2: K=1024 -> 256-class 8-phase, 256 blocks (1/CU exact)
  k_gemm8p<256, 256><<<256, 512, 0, stream>>>(h0, w1b, 1024, 1024, 4, b1, h1);
  k_gemm8p<128, 256><<<256, 512, 0, stream>>>(h1, w2b, 1024, 512, 2, b2, h2);
  // head: flatmm v4 — depth-3 named pipeline, waves_per_eu(2,2) pins VGPR budget
  k_flat_head<<<2240, 256, 0, stream>>>(h2, bsh, bhd, out_pi, out_mu, out_tril);
}

// Round 11
// 191.527 us; speedup vs baseline: 1.1622x; 1.1622x over previous
//
#include <hip/hip_runtime.h>
#include <hip/hip_bf16.h>
#include <cstdint>
#include <cstddef>

typedef __attribute__((ext_vector_type(8))) _Float16 half8;
typedef __attribute__((ext_vector_type(4))) float f32x4;
typedef __attribute__((ext_vector_type(8))) unsigned short ushort8v;
typedef __attribute__((ext_vector_type(4))) unsigned short ushort4v;

__device__ __forceinline__ unsigned short f2h_bits(float x) {
  _Float16 h = (_Float16)x;
  union { _Float16 h; unsigned short u; } cv; cv.h = h; return cv.u;
}

__device__ __forceinline__ void barrier_raw() {
  asm volatile("" ::: "memory");
  __builtin_amdgcn_s_barrier();
  asm volatile("" ::: "memory");
}
template<int N> __device__ __forceinline__ void vmw() {
  static_assert(N == 0 || N == 3 || N == 4, "unsupported vmcnt");
  if constexpr (N == 0) asm volatile("s_waitcnt vmcnt(0)" ::: "memory");
  if constexpr (N == 3) asm volatile("s_waitcnt vmcnt(3)" ::: "memory");
  if constexpr (N == 4) asm volatile("s_waitcnt vmcnt(4)" ::: "memory");
}
__device__ __forceinline__ void lgkm0() {
  asm volatile("s_waitcnt lgkmcnt(0)" ::: "memory");
}

// ---------------- prep kernels ----------------

__global__ __launch_bounds__(256) void k_f32_to_f16(const float* __restrict__ src,
                                                    unsigned short* __restrict__ dst, int n4) {
  int i = blockIdx.x * 256 + threadIdx.x;
  if (i >= n4) return;
  float4 v = ((const float4*)src)[i];
  ushort4v o;
  o[0] = f2h_bits(v.x); o[1] = f2h_bits(v.y); o[2] = f2h_bits(v.z); o[3] = f2h_bits(v.w);
  ((ushort4v*)dst)[i] = o;
}

__global__ __launch_bounds__(256) void k_transpose_f16(const float* __restrict__ W,
                                                       unsigned short* __restrict__ Wt,
                                                       int Kd, int N) {
  int tid = blockIdx.x * 256 + threadIdx.x;
  int total = (Kd >> 3) * N;
  if (tid >= total) return;
  int kc = tid / N;
  int n  = tid - kc * N;
  int k0 = kc << 3;
  ushort8v o;
#pragma unroll
  for (int j = 0; j < 8; ++j) o[j] = f2h_bits(W[(size_t)(k0 + j) * N + n]);
  *(ushort8v*)(&Wt[(size_t)n * Kd + k0]) = o;
}

// q in [0,160) -> (i, j) for pad-to-4 tril rows (lens 4,4,4,4,8,8,8,8,12,12,12,12,16x4)
__device__ __forceinline__ void q_to_ij(int q, int& i, int& j) {
  if (q < 16)      { i = q >> 2;              j = q & 3; }
  else if (q < 48) { i = 4 + ((q - 16) >> 3); j = (q - 16) & 7; }
  else if (q < 96) { int u = q - 48; int d = u / 12; i = 8 + d;  j = u - 12 * d; }
  else             { i = 12 + ((q - 96) >> 4); j = (q - 96) & 15; }
}

// Head weight [1536][512] fp16 row-major + bias [1536] f32.
// rows: 0..127 mu | 128..1407 tril pad-to-4 (k*160+q; zero row if j>i) | 1408..1415 pi | pad.
__global__ __launch_bounds__(256) void k_build_head(
    const float* __restrict__ Wmu, const float* __restrict__ Wt,
    const float* __restrict__ Wpi,
    const float* __restrict__ bmu, const float* __restrict__ bt,
    const float* __restrict__ bpi,
    unsigned short* __restrict__ whd, float* __restrict__ bhd)
{
  int tid = blockIdx.x * 256 + threadIdx.x;   // (r, octet): 1536*64
  if (tid >= 1536 * 64) return;
  int r  = tid >> 6;
  int d0 = (tid & 63) << 3;

  const float* src = nullptr; int stride = 0;
  if (r < 128) { src = Wmu + r; stride = 128; }
  else if (r < 1408) {
    int rr = r - 128, k = rr / 160, q = rr - k * 160, i, j;
    q_to_ij(q, i, j);
    if (j <= i) { src = Wt + k * 136 + ((i * (i + 1)) >> 1) + j; stride = 1088; }
  } else if (r < 1416) { src = Wpi + (r - 1408); stride = 8; }

  ushort8v o;
#pragma unroll
  for (int jj = 0; jj < 8; ++jj)
    o[jj] = src ? f2h_bits(src[(size_t)(d0 + jj) * stride]) : (unsigned short)0;
  *(ushort8v*)(&whd[(size_t)r * 512 + d0]) = o;

  if (d0 == 0) {
    float b = 0.f;
    if (r < 128) b = bmu[r];
    else if (r < 1408) {
      int rr = r - 128, k = rr / 160, q = rr - k * 160, i, j;
      q_to_ij(q, i, j);
      if (j <= i) b = bt[k * 136 + ((i * (i + 1)) >> 1) + j];
    } else if (r < 1416) b = bpi[r - 1408];
    bhd[r] = b;
  }
}

// zero-tail: writes zeros at tril (row, k, i, j>=len_i), len_i = 4*ceil((i+1)/4).
// 24 float4 per (row,k): i<4 -> 3 (j0=4,8,12); i in 4..7 -> 2 (8,12); 8..11 -> 1 (12).
__global__ __launch_bounds__(256) void k_zero_tail(float* __restrict__ out_tril, int total) {
  int tid = blockIdx.x * 256 + threadIdx.x;
  if (tid >= total) return;                    // total = 16384*8*24
  int row = tid / 192;
  int rem = tid - row * 192;
  int k   = rem / 24;
  int z   = rem - k * 24;
  int i, j0;
  if (z < 12)      { i = z / 3;            j0 = 4 + 4 * (z - 3 * i); }
  else if (z < 20) { int u = z - 12; i = 4 + (u >> 1); j0 = 8 + 4 * (u & 1); }
  else             { i = 8 + (z - 20);     j0 = 12; }
  *(float4*)&out_tril[(size_t)row * 2048 + (k << 8) + (i << 4) + j0] =
      make_float4(0.f, 0.f, 0.f, 0.f);
}

// ---- shared epilogue helpers (swapped-operand layout: row=l15-side, col=lk*4+reg) ----

__device__ __forceinline__ void epi_relu_h(const f32x4& a, const float* bias, int col0,
                                           unsigned short* Hout, size_t row, int N) {
  float4 b4 = *(const float4*)&bias[col0];
  ushort4v o;
  float v0 = a[0] + b4.x; o[0] = f2h_bits(v0 > 0.f ? v0 : 0.f);
  float v1 = a[1] + b4.y; o[1] = f2h_bits(v1 > 0.f ? v1 : 0.f);
  float v2 = a[2] + b4.z; o[2] = f2h_bits(v2 > 0.f ? v2 : 0.f);
  float v3 = a[3] + b4.w; o[3] = f2h_bits(v3 > 0.f ? v3 : 0.f);
  *(ushort4v*)&Hout[row * N + col0] = o;
}

// head epilogue for the N=1536 pad-to-4 layout
__device__ __forceinline__ void epi_head(const f32x4& a, const float* bias, int col0,
                                         size_t row, float* out_pi, float* out_mu,
                                         float* out_tril) {
  if (col0 >= 1416) return;   // pad
  float4 b4 = *(const float4*)&bias[col0];
  float v[4] = { a[0] + b4.x, a[1] + b4.y, a[2] + b4.z, a[3] + b4.w };
  if (col0 < 128) {
    *(float4*)&out_mu[row * 128 + col0] = make_float4(v[0], v[1], v[2], v[3]);
  } else if (col0 < 1408) {
    const int cc = col0 - 128;
    const int k  = cc / 160;
    const int q  = cc - k * 160;          // 4-aligned; whole chunk in one i-row
    int i, j0;
    q_to_ij(q, i, j0);
#pragma unroll
    for (int r = 0; r < 4; ++r) if (j0 + r == i) v[r] = expf(v[r]);   // diagonal
    // pad-within-4 (j>i) slots: zero B-row + zero bias -> v==0, correct output zeros
    *(float4*)&out_tril[row * 2048 + (k << 8) + (i << 4) + j0] =
        make_float4(v[0], v[1], v[2], v[3]);
  } else {
    // pi: lk=0 holds cols 1408-11, lk=1 holds 1412-15 (lane^16 pairs); lk>=2 are pad
    float m4 = fmaxf(fmaxf(v[0], v[1]), fmaxf(v[2], v[3]));
    float mx = fmaxf(m4, __shfl_xor(m4, 16));
    float e[4], s4 = 0.f;
#pragma unroll
    for (int r = 0; r < 4; ++r) { e[r] = expf(v[r] - mx); s4 += e[r]; }
    float sm = s4 + __shfl_xor(s4, 16);
    *(float4*)&out_pi[row * 8 + (col0 - 1408)] =
        make_float4(e[0] / sm, e[1] / sm, e[2] / sm, e[3] / sm);
  }
}

// -------- 3-buffer counted-vmcnt 128x128 GEMM (rounds 6-10 verified) --------

template<int EPI>
__global__ __launch_bounds__(256) void k_gemm3b(
    const unsigned short* __restrict__ A,
    const unsigned short* __restrict__ Bt,
    int Kd, int N, int nNb,
    const float* __restrict__ bias,
    unsigned short* __restrict__ Hout,
    float* __restrict__ out_pi,
    float* __restrict__ out_mu,
    float* __restrict__ out_tril)
{
  __shared__ unsigned short Ald[3][128 * 32];
  __shared__ unsigned short Bld[3][128 * 32];

  const int tid  = threadIdx.x;
  const int lane = tid & 63;
  const int wv   = tid >> 6;
  const int wr   = wv >> 1;
  const int wc   = wv & 1;
  const int l15  = lane & 15;
  const int lk   = lane >> 4;

  const int cpx = gridDim.x >> 3;
  const int bid = blockIdx.x;
  const int swz = (bid & 7) * cpx + (bid >> 3);
  const int bm  = (swz / nNb) << 7;
  const int bn  = (swz % nNb) << 7;

  f32x4 acc[4][4] = {};

  const unsigned short* aBase = A  + (size_t)bm * Kd;
  const unsigned short* bBase = Bt + (size_t)bn * Kd;

  const int xo = ((lk ^ ((l15 >> 1) & 3)) << 3);

  auto stage = [&](int bb, int kt) {
    const int k0 = kt << 5;
#pragma unroll
    for (int i = 0; i < 2; ++i) {
      const int cbase = (wv << 6) + (i << 8);
      const int c_    = cbase + lane;
      const int row   = c_ >> 2;
      const int sc    = (((c_ & 3) ^ ((c_ >> 3) & 3)) << 3);
      __builtin_amdgcn_global_load_lds(
          (const __attribute__((address_space(1))) void*)(aBase + (size_t)row * Kd + k0 + sc),
          (__attribute__((address_space(3))) void*)(&Ald[bb][cbase << 3]),
          16, 0, 0);
      __builtin_amdgcn_global_load_lds(
          (const __attribute__((address_space(1))) void*)(bBase + (size_t)row * Kd + k0 + sc),
          (__attribute__((address_space(3))) void*)(&Bld[bb][cbase << 3]),
          16, 0, 0);
    }
  };

  const int nk = Kd >> 5;
  stage(0, 0);
  stage(1, 1);
  vmw<4>();
  barrier_raw();

  int i0 = 0, i1 = 1, i2 = 2;
  for (int kt = 0; kt < nk; ++kt) {
    if (kt + 2 < nk) stage(i2, kt + 2);

    half8 af[4], bfr[4];
#pragma unroll
    for (int m = 0; m < 4; ++m)
      af[m]  = *(const half8*)&Ald[i0][((wr << 6) + (m << 4) + l15) * 32 + xo];
#pragma unroll
    for (int n = 0; n < 4; ++n)
      bfr[n] = *(const half8*)&Bld[i0][((wc << 6) + (n << 4) + l15) * 32 + xo];

    __builtin_amdgcn_s_setprio(1);
#pragma unroll
    for (int m = 0; m < 4; ++m)
#pragma unroll
      for (int n = 0; n < 4; ++n)
        acc[m][n] = __builtin_amdgcn_mfma_f32_16x16x32_f16(bfr[n], af[m], acc[m][n], 0, 0, 0);
    __builtin_amdgcn_s_setprio(0);

    if (kt + 1 < nk) {
      if (kt + 2 < nk) vmw<4>();
      else             vmw<0>();
      barrier_raw();
    }
    const int t = i0; i0 = i1; i1 = i2; i2 = t;
  }

#pragma unroll
  for (int m = 0; m < 4; ++m) {
    const size_t row = bm + (wr << 6) + (m << 4) + l15;
#pragma unroll
    for (int n = 0; n < 4; ++n) {
      const int col0 = bn + (wc << 6) + (n << 4) + (lk << 2);
      if (EPI == 0) epi_relu_h(acc[m][n], bias, col0, Hout, row, N);
      else          epi_head(acc[m][n], bias, col0, row, out_pi, out_mu, out_tril);
    }
  }
}

// -------- 8-phase counted-vmcnt GEMM (rounds 4-10 verified) — L1/L2 --------

template<int NH, int M_rep>
__device__ __forceinline__ void mfma_phase(const half8* af, const half8* bf,
                                           f32x4 (*acc)[4]) {
  __builtin_amdgcn_s_setprio(1);
#pragma unroll
  for (int m = 0; m < M_rep; ++m) {
    acc[m][NH * 2 + 0] = __builtin_amdgcn_mfma_f32_16x16x32_f16(bf[0], af[m], acc[m][NH * 2 + 0], 0, 0, 0);
    acc[m][NH * 2 + 1] = __builtin_amdgcn_mfma_f32_16x16x32_f16(bf[1], af[m], acc[m][NH * 2 + 1], 0, 0, 0);
  }
  __builtin_amdgcn_s_setprio(0);
}

template<int BM, int BN>
__global__ __launch_bounds__(512) void k_gemm8p(
    const unsigned short* __restrict__ A,
    const unsigned short* __restrict__ Bt,
    int Kd, int N, int nNb,
    const float* __restrict__ bias,
    unsigned short* __restrict__ Hout)
{
  constexpr int M_rep = BM / 32;
  constexpr int A_LD  = BM / 128;
  constexpr int B_LD  = BN / 128;
  constexpr int WN    = A_LD + B_LD;

  __shared__ unsigned short Ald[2][2][BM * 32];
  __shared__ unsigned short Bld[2][2][BN * 32];

  const int tid  = threadIdx.x;
  const int lane = tid & 63;
  const int wid  = tid >> 6;
  const int wm   = wid >> 2;
  const int wn   = wid & 3;
  const int l15  = lane & 15;
  const int lk   = lane >> 4;

  const int cpx = gridDim.x >> 3;
  const int bid = blockIdx.x;
  const int swz = (bid & 7) * cpx + (bid >> 3);
  const int bm  = (swz / nNb) * BM;
  const int bn  = (swz % nNb) * BN;

  const unsigned short* aBase = A  + (size_t)bm * Kd;
  const unsigned short* bBase = Bt + (size_t)bn * Kd;

  f32x4 acc[M_rep][4] = {};

  const int xo   = ((lk ^ ((l15 >> 1) & 3)) << 3);
  const int rowA = wm * (BM / 2) + l15;
  const int colB = wn * 64 + l15;

  auto stageA = [&](int bb, int h, int k0) {
#pragma unroll
    for (int i = 0; i < A_LD; ++i) {
      const int cbase = (wid << 6) + (i << 9);
      const int c_    = cbase + lane;
      const int row   = c_ >> 2;
      const int sc    = (((c_ & 3) ^ ((c_ >> 3) & 3)) << 3);
      __builtin_amdgcn_global_load_lds(
          (const __attribute__((address_space(1))) void*)(aBase + (size_t)row * Kd + k0 + h * 32 + sc),
          (__attribute__((address_space(3))) void*)(&Ald[bb][h][(size_t)cbase << 3]),
          16, 0, 0);
    }
  };
  auto stageB = [&](int bb, int h, int k0) {
#pragma unroll
    for (int i = 0; i < B_LD; ++i) {
      const int cbase = (wid << 6) + (i << 9);
      const int c_    = cbase + lane;
      const int row   = c_ >> 2;
      const int sc    = (((c_ & 3) ^ ((c_ >> 3) & 3)) << 3);
      __builtin_amdgcn_global_load_lds(
          (const __attribute__((address_space(1))) void*)(bBase + (size_t)row * Kd + k0 + h * 32 + sc),
          (__attribute__((address_space(3))) void*)(&Bld[bb][h][(size_t)cbase << 3]),
          16, 0, 0);
    }
  };

#define RD_A(kk)                                                                 \
  {                                                                              \
    _Pragma("unroll")                                                            \
    for (int m = 0; m < M_rep; ++m)                                              \
      af[m] = *(const half8*)&Ald[cur][kk][(size_t)(rowA + m * 16) * 32 + xo];   \
  }
#define RD_B(kk, nh)                                                             \
  {                                                                              \
    _Pragma("unroll")                                                            \
    for (int n2 = 0; n2 < 2; ++n2)                                               \
      bf[n2] = *(const half8*)&Bld[cur][kk][(size_t)(colB + ((nh) * 2 + n2) * 16) * 32 + xo]; \
  }

  const int nk = Kd >> 6;
  stageA(0, 0, 0); stageB(0, 0, 0); stageA(0, 1, 0); stageB(0, 1, 0);
  vmw<WN>();
  barrier_raw();

  int cur = 0;
  for (int kt = 0; kt < nk; ++kt) {
    const bool pre = (kt + 1 < nk);
    const int  k0n = (kt + 1) << 6;
    half8 af[M_rep], bf[2];

    RD_A(0); RD_B(0, 0);
    if (pre) stageA(cur ^ 1, 0, k0n);
    barrier_raw(); lgkm0();
    mfma_phase<0, M_rep>(af, bf, acc);
    barrier_raw();

    RD_B(0, 1);
    if (pre) stageB(cur ^ 1, 0, k0n);
    barrier_raw(); lgkm0();
    mfma_phase<1, M_rep>(af, bf, acc);
    if (pre) vmw<WN>(); else vmw<0>();
    barrier_raw();

    RD_A(1); RD_B(1, 0);
    if (pre) stageA(cur ^ 1, 1, k0n);
    barrier_raw(); lgkm0();
    mfma_phase<0, M_rep>(af, bf, acc);
    barrier_raw();

    RD_B(1, 1);
    if (pre) stageB(cur ^ 1, 1, k0n);
    barrier_raw(); lgkm0();
    mfma_phase<1, M_rep>(af, bf, acc);
    if (pre) vmw<WN>();
    barrier_raw();

    cur ^= 1;
  }
#undef RD_A
#undef RD_B

#pragma unroll
  for (int m = 0; m < M_rep; ++m) {
    const size_t row = bm + wm * (BM / 2) + (m << 4) + l15;
#pragma unroll
    for (int n = 0; n < 4; ++n) {
      const int col0 = bn + wn * 64 + (n << 4) + (lk << 2);
      epi_relu_h(acc[m][n], bias, col0, Hout, row, N);
    }
  }
}

// ---------------- launch ----------------

extern "C" void kernel_launch(void* const* d_in, const int* in_sizes, int n_in,
                              void* d_out, int out_size, void* d_ws, size_t ws_size,
                              hipStream_t stream)
{
  const float* x   = (const float*)d_in[0];
  const float* W0  = (const float*)d_in[1];
  const float* b0  = (const float*)d_in[2];
  const float* W1  = (const float*)d_in[3];
  const float* b1  = (const float*)d_in[4];
  const float* W2  = (const float*)d_in[5];
  const float* b2  = (const float*)d_in[6];
  const float* Wpi = (const float*)d_in[7];
  const float* bpi = (const float*)d_in[8];
  const float* Wmu = (const float*)d_in[9];
  const float* bmu = (const float*)d_in[10];
  const float* Wt  = (const float*)d_in[11];
  const float* bt  = (const float*)d_in[12];

  char* ws = (char*)d_ws;
  unsigned short* xh  = (unsigned short*)(ws);             //  8,388,608 B
  unsigned short* h0  = (unsigned short*)(ws + 8388608);   // 33,554,432 B
  unsigned short* h1  = (unsigned short*)(ws + 41943040);  // 33,554,432 B
  unsigned short* h2  = (unsigned short*)(ws + 8388608);   // 16,777,216 B (aliases h0 — dead by then)
  unsigned short* w0b = (unsigned short*)(ws + 75497472);  //    524,288 B [1024][256]
  unsigned short* w1b = (unsigned short*)(ws + 76021760);  //  2,097,152 B [1024][1024]
  unsigned short* w2b = (unsigned short*)(ws + 78118912);  //  1,048,576 B [512][1024]
  unsigned short* whd = (unsigned short*)(ws + 79167488);  //  1,572,864 B [1536][512]
  float*          bhd = (float*)         (ws + 81526784);  //      6,144 B [1536]

  float* out_pi   = (float*)d_out;                // 131072
  float* out_mu   = (float*)d_out + 131072;       // 2097152
  float* out_tril = (float*)d_out + 2228224;      // 33554432

  // prep
  k_f32_to_f16<<<4096, 256, 0, stream>>>(x, xh, 1048576);
  k_transpose_f16<<<128, 256, 0, stream>>>(W0, w0b, 256, 1024);
  k_transpose_f16<<<512, 256, 0, stream>>>(W1, w1b, 1024, 1024);
  k_transpose_f16<<<256, 256, 0, stream>>>(W2, w2b, 1024, 512);
  k_build_head<<<384, 256, 0, stream>>>(Wmu, Wt, Wpi, bmu, bt, bpi, whd, bhd);

  // L0: short-K (256) -> 3-buffer 128^2 counted-vmcnt, 1024 blocks
  k_gemm3b<0><<<1024, 256, 0, stream>>>(xh, w0b, 256, 1024, 8, b0, h0,
                                        nullptr, nullptr, nullptr);
  // L1/L2: K=1024 -> 256-class 8-phase, 256 blocks (1/CU exact)
  k_gemm8p<256, 256><<<256, 512, 0, stream>>>(h0, w1b, 1024, 1024, 4, b1, h1);
  k_gemm8p<128, 256><<<256, 512, 0, stream>>>(h1, w2b, 1024, 512, 2, b2, h2);
  // upper-tail zeros of tril (disjoint from head's writes)
  k_zero_tail<<<12288, 256, 0, stream>>>(out_tril, 16384 * 8 * 24);
  // head: N=1536 pad-to-4 packed layout, 3-buffer 128^2 counted-vmcnt, 1536 blocks
  k_gemm3b<1><<<1536, 256, 0, stream>>>(h2, whd, 512, 1536, 12, bhd, nullptr,
                                        out_pi, out_mu, out_tril);
}

// Round 12
// 186.630 us; speedup vs baseline: 1.1927x; 1.0262x over previous
//
#include <hip/hip_runtime.h>
#include <hip/hip_bf16.h>
#include <cstdint>
#include <cstddef>

typedef __attribute__((ext_vector_type(8))) _Float16 half8;
typedef __attribute__((ext_vector_type(4))) float f32x4;
typedef __attribute__((ext_vector_type(8))) unsigned short ushort8v;
typedef __attribute__((ext_vector_type(4))) unsigned short ushort4v;

__device__ __forceinline__ unsigned short f2h_bits(float x) {
  _Float16 h = (_Float16)x;
  union { _Float16 h; unsigned short u; } cv; cv.h = h; return cv.u;
}

__device__ __forceinline__ void barrier_raw() {
  asm volatile("" ::: "memory");
  __builtin_amdgcn_s_barrier();
  asm volatile("" ::: "memory");
}
template<int N> __device__ __forceinline__ void vmw() {
  static_assert(N == 0 || N == 3 || N == 4, "unsupported vmcnt");
  if constexpr (N == 0) asm volatile("s_waitcnt vmcnt(0)" ::: "memory");
  if constexpr (N == 3) asm volatile("s_waitcnt vmcnt(3)" ::: "memory");
  if constexpr (N == 4) asm volatile("s_waitcnt vmcnt(4)" ::: "memory");
}
__device__ __forceinline__ void lgkm0() {
  asm volatile("s_waitcnt lgkmcnt(0)" ::: "memory");
}

// ---------------- prep kernels ----------------

__global__ __launch_bounds__(256) void k_transpose_f16(const float* __restrict__ W,
                                                       unsigned short* __restrict__ Wt,
                                                       int Kd, int N) {
  int tid = blockIdx.x * 256 + threadIdx.x;
  int total = (Kd >> 3) * N;
  if (tid >= total) return;
  int kc = tid / N;
  int n  = tid - kc * N;
  int k0 = kc << 3;
  ushort8v o;
#pragma unroll
  for (int j = 0; j < 8; ++j) o[j] = f2h_bits(W[(size_t)(k0 + j) * N + n]);
  *(ushort8v*)(&Wt[(size_t)n * Kd + k0]) = o;
}

// Build unpacked head weight whd [2304][512] fp16 and bias bhd [2304] f32.
// rows 0..127: mu; 128..2175: tril unpacked (k*256+i*16+j, zero if j>i);
// 2176..2183: pi; 2184..2303: zero pad.  (R6-verified)
__global__ __launch_bounds__(256) void k_build_head(
    const float* __restrict__ Wmu, const float* __restrict__ Wt,
    const float* __restrict__ Wpi,
    const float* __restrict__ bmu, const float* __restrict__ bt,
    const float* __restrict__ bpi,
    unsigned short* __restrict__ whd, float* __restrict__ bhd)
{
  int tid = blockIdx.x * 256 + threadIdx.x;   // (r, d-chunk of 8): 2304*64
  if (tid >= 2304 * 64) return;
  int r  = tid >> 6;
  int d0 = (tid & 63) << 3;

  const float* src = nullptr; int stride = 0;
  if (r < 128) { src = Wmu + r; stride = 128; }
  else if (r < 2176) {
    int rU = r - 128, k = rU >> 8, i = (rU >> 4) & 15, j = rU & 15;
    if (j <= i) { src = Wt + k * 136 + ((i * (i + 1)) >> 1) + j; stride = 1088; }
  } else if (r < 2184) { src = Wpi + (r - 2176); stride = 8; }

  ushort8v o;
#pragma unroll
  for (int jj = 0; jj < 8; ++jj)
    o[jj] = src ? f2h_bits(src[(size_t)(d0 + jj) * stride]) : (unsigned short)0;
  *(ushort8v*)(&whd[(size_t)r * 512 + d0]) = o;

  if (d0 == 0) {
    float b = 0.f;
    if (r < 128) b = bmu[r];
    else if (r < 2176) {
      int rU = r - 128, k = rU >> 8, i = (rU >> 4) & 15, j = rU & 15;
      if (j <= i) b = bt[k * 136 + ((i * (i + 1)) >> 1) + j];
    } else if (r < 2184) b = bpi[r - 2176];
    bhd[r] = b;
  }
}

// ---- shared epilogue helpers (swapped-operand layout: row=l15-side, col=lk*4+reg) ----

__device__ __forceinline__ void epi_relu_h(const f32x4& a, const float* bias, int col0,
                                           unsigned short* Hout, size_t row, int N) {
  float4 b4 = *(const float4*)&bias[col0];
  ushort4v o;
  float v0 = a[0] + b4.x; o[0] = f2h_bits(v0 > 0.f ? v0 : 0.f);
  float v1 = a[1] + b4.y; o[1] = f2h_bits(v1 > 0.f ? v1 : 0.f);
  float v2 = a[2] + b4.z; o[2] = f2h_bits(v2 > 0.f ? v2 : 0.f);
  float v3 = a[3] + b4.w; o[3] = f2h_bits(v3 > 0.f ? v3 : 0.f);
  *(ushort4v*)&Hout[row * N + col0] = o;
}

// head epilogue, N=2304 layout (R6-verified)
__device__ __forceinline__ void epi_head(const f32x4& a, const float* bias, int col0,
                                         size_t row, float* out_pi, float* out_mu,
                                         float* out_tril) {
  if (col0 >= 2184) return;   // pad
  float4 b4 = *(const float4*)&bias[col0];
  float v[4] = { a[0] + b4.x, a[1] + b4.y, a[2] + b4.z, a[3] + b4.w };
  if (col0 < 128) {
    *(float4*)&out_mu[row * 128 + col0] = make_float4(v[0], v[1], v[2], v[3]);
  } else if (col0 < 2176) {
    const int cc0 = col0 - 128;
    const int i   = (cc0 >> 4) & 15;
    const int j0  = cc0 & 15;
#pragma unroll
    for (int r = 0; r < 4; ++r) if (j0 + r == i) v[r] = expf(v[r]);
    *(float4*)&out_tril[row * 2048 + cc0] = make_float4(v[0], v[1], v[2], v[3]);
  } else {
    // pi: lanes lk=0 hold cols 2176-79, lk=1 hold 2180-83 for the same row (lane^16)
    float m4 = fmaxf(fmaxf(v[0], v[1]), fmaxf(v[2], v[3]));
    float mx = fmaxf(m4, __shfl_xor(m4, 16));
    float e[4], s4 = 0.f;
#pragma unroll
    for (int r = 0; r < 4; ++r) { e[r] = expf(v[r] - mx); s4 += e[r]; }
    float sm = s4 + __shfl_xor(s4, 16);
    *(float4*)&out_pi[row * 8 + (col0 - 2176)] =
        make_float4(e[0] / sm, e[1] / sm, e[2] / sm, e[3] / sm);
  }
}

// -------- L0: fused f32->f16 GEMM, 128x128, 2-buffer, T14-split A-staging --------
// A = x [16384][256] f32 read directly; per thread 4 float4 loads issued BEFORE
// compute(t) (latency hides under MFMA), cvt+ds_write AFTER compute, one sync.
// B = w0b f16 via global_load_lds (drained by the same sync). XOR swizzle as verified.

__global__ __launch_bounds__(256) void k_gemm_l0(
    const float* __restrict__ X,
    const unsigned short* __restrict__ Bt,   // [1024][256] f16
    const float* __restrict__ bias,
    unsigned short* __restrict__ Hout)       // h0 [16384][1024] f16
{
  constexpr int Kd = 256, N = 1024, nNb = 8;
  __shared__ unsigned short Ald[2][128 * 32];
  __shared__ unsigned short Bld[2][128 * 32];

  const int tid  = threadIdx.x;
  const int lane = tid & 63;
  const int wv   = tid >> 6;
  const int wr   = wv >> 1;
  const int wc   = wv & 1;
  const int l15  = lane & 15;
  const int lk   = lane >> 4;

  const int cpx = gridDim.x >> 3;
  const int bid = blockIdx.x;
  const int swz = (bid & 7) * cpx + (bid >> 3);
  const int bm  = (swz / nNb) << 7;
  const int bn  = (swz % nNb) << 7;

  f32x4 acc[4][4] = {};

  const float*          aBase = X  + (size_t)bm * Kd;
  const unsigned short* bBase = Bt + (size_t)bn * Kd;

  const int xo = ((lk ^ ((l15 >> 1) & 3)) << 3);

  // staging chunk coords (2 chunks/thread; identical swizzle math to verified stage())
  const int c0   = (wv << 6) + lane;            // chunk ids
  const int c1   = c0 + 256;
  const int row0 = c0 >> 2, row1 = c1 >> 2;
  const int sc0  = (((c0 & 3) ^ ((c0 >> 3) & 3)) << 3);
  const int sc1  = (((c1 & 3) ^ ((c1 >> 3) & 3)) << 3);

  auto issueB = [&](int bb, int kt) {
    const int k0 = kt << 5;
#pragma unroll
    for (int i = 0; i < 2; ++i) {
      const int cbase = (wv << 6) + (i << 8);
      const int c_    = cbase + lane;
      const int row   = c_ >> 2;
      const int sc    = (((c_ & 3) ^ ((c_ >> 3) & 3)) << 3);
      __builtin_amdgcn_global_load_lds(
          (const __attribute__((address_space(1))) void*)(bBase + (size_t)row * Kd + k0 + sc),
          (__attribute__((address_space(3))) void*)(&Bld[bb][cbase << 3]),
          16, 0, 0);
    }
  };

  float4 p0, p1, p2, p3;                         // held one step (T14 split)
  auto loadA = [&](int kt) {
    const int k0 = kt << 5;
    const float* s0 = aBase + (size_t)row0 * Kd + k0 + sc0;
    const float* s1 = aBase + (size_t)row1 * Kd + k0 + sc1;
    p0 = *(const float4*)(s0);
    p1 = *(const float4*)(s0 + 4);
    p2 = *(const float4*)(s1);
    p3 = *(const float4*)(s1 + 4);
  };
  auto writeA = [&](int bb) {
    half8 h0, h1;
    h0[0]=(_Float16)p0.x; h0[1]=(_Float16)p0.y; h0[2]=(_Float16)p0.z; h0[3]=(_Float16)p0.w;
    h0[4]=(_Float16)p1.x; h0[5]=(_Float16)p1.y; h0[6]=(_Float16)p1.z; h0[7]=(_Float16)p1.w;
    h1[0]=(_Float16)p2.x; h1[1]=(_Float16)p2.y; h1[2]=(_Float16)p2.z; h1[3]=(_Float16)p2.w;
    h1[4]=(_Float16)p3.x; h1[5]=(_Float16)p3.y; h1[6]=(_Float16)p3.z; h1[7]=(_Float16)p3.w;
    *(half8*)&Ald[bb][c0 << 3] = h0;
    *(half8*)&Ald[bb][c1 << 3] = h1;
  };

  const int nk = Kd >> 5;   // 8
  loadA(0); issueB(0, 0); writeA(0);
  __syncthreads();

  int cur = 0;
  for (int kt = 0; kt < nk; ++kt) {
    const bool pre = (kt + 1 < nk);
    if (pre) { loadA(kt + 1); issueB(cur ^ 1, kt + 1); }   // issue before compute

    half8 af[4], bfr[4];
#pragma unroll
    for (int m = 0; m < 4; ++m)
      af[m]  = *(const half8*)&Ald[cur][((wr << 6) + (m << 4) + l15) * 32 + xo];
#pragma unroll
    for (int n = 0; n < 4; ++n)
      bfr[n] = *(const half8*)&Bld[cur][((wc << 6) + (n << 4) + l15) * 32 + xo];

    __builtin_amdgcn_s_setprio(1);
#pragma unroll
    for (int m = 0; m < 4; ++m)
#pragma unroll
      for (int n = 0; n < 4; ++n)
        acc[m][n] = __builtin_amdgcn_mfma_f32_16x16x32_f16(bfr[n], af[m], acc[m][n], 0, 0, 0);
    __builtin_amdgcn_s_setprio(0);

    if (pre) writeA(cur ^ 1);       // cvt+LDS write after compute (loads have landed)
    __syncthreads();                // drains B glds + publishes A writes
    cur ^= 1;
  }

#pragma unroll
  for (int m = 0; m < 4; ++m) {
    const size_t row = bm + (wr << 6) + (m << 4) + l15;
#pragma unroll
    for (int n = 0; n < 4; ++n) {
      const int col0 = bn + (wc << 6) + (n << 4) + (lk << 2);
      epi_relu_h(acc[m][n], bias, col0, Hout, row, N);
    }
  }
}

// -------- 3-buffer counted-vmcnt 128x128 GEMM (rounds 6-11 verified) — head --------

template<int EPI>
__global__ __launch_bounds__(256) void k_gemm3b(
    const unsigned short* __restrict__ A,
    const unsigned short* __restrict__ Bt,
    int Kd, int N, int nNb,
    const float* __restrict__ bias,
    unsigned short* __restrict__ Hout,
    float* __restrict__ out_pi,
    float* __restrict__ out_mu,
    float* __restrict__ out_tril)
{
  __shared__ unsigned short Ald[3][128 * 32];
  __shared__ unsigned short Bld[3][128 * 32];

  const int tid  = threadIdx.x;
  const int lane = tid & 63;
  const int wv   = tid >> 6;
  const int wr   = wv >> 1;
  const int wc   = wv & 1;
  const int l15  = lane & 15;
  const int lk   = lane >> 4;

  const int cpx = gridDim.x >> 3;
  const int bid = blockIdx.x;
  const int swz = (bid & 7) * cpx + (bid >> 3);
  const int bm  = (swz / nNb) << 7;
  const int bn  = (swz % nNb) << 7;

  f32x4 acc[4][4] = {};

  const unsigned short* aBase = A  + (size_t)bm * Kd;
  const unsigned short* bBase = Bt + (size_t)bn * Kd;

  const int xo = ((lk ^ ((l15 >> 1) & 3)) << 3);

  auto stage = [&](int bb, int kt) {
    const int k0 = kt << 5;
#pragma unroll
    for (int i = 0; i < 2; ++i) {
      const int cbase = (wv << 6) + (i << 8);
      const int c_    = cbase + lane;
      const int row   = c_ >> 2;
      const int sc    = (((c_ & 3) ^ ((c_ >> 3) & 3)) << 3);
      __builtin_amdgcn_global_load_lds(
          (const __attribute__((address_space(1))) void*)(aBase + (size_t)row * Kd + k0 + sc),
          (__attribute__((address_space(3))) void*)(&Ald[bb][cbase << 3]),
          16, 0, 0);
      __builtin_amdgcn_global_load_lds(
          (const __attribute__((address_space(1))) void*)(bBase + (size_t)row * Kd + k0 + sc),
          (__attribute__((address_space(3))) void*)(&Bld[bb][cbase << 3]),
          16, 0, 0);
    }
  };

  const int nk = Kd >> 5;
  stage(0, 0);
  stage(1, 1);
  vmw<4>();
  barrier_raw();

  int i0 = 0, i1 = 1, i2 = 2;
  for (int kt = 0; kt < nk; ++kt) {
    if (kt + 2 < nk) stage(i2, kt + 2);

    half8 af[4], bfr[4];
#pragma unroll
    for (int m = 0; m < 4; ++m)
      af[m]  = *(const half8*)&Ald[i0][((wr << 6) + (m << 4) + l15) * 32 + xo];
#pragma unroll
    for (int n = 0; n < 4; ++n)
      bfr[n] = *(const half8*)&Bld[i0][((wc << 6) + (n << 4) + l15) * 32 + xo];

    __builtin_amdgcn_s_setprio(1);
#pragma unroll
    for (int m = 0; m < 4; ++m)
#pragma unroll
      for (int n = 0; n < 4; ++n)
        acc[m][n] = __builtin_amdgcn_mfma_f32_16x16x32_f16(bfr[n], af[m], acc[m][n], 0, 0, 0);
    __builtin_amdgcn_s_setprio(0);

    if (kt + 1 < nk) {
      if (kt + 2 < nk) vmw<4>();
      else             vmw<0>();
      barrier_raw();
    }
    const int t = i0; i0 = i1; i1 = i2; i2 = t;
  }

#pragma unroll
  for (int m = 0; m < 4; ++m) {
    const size_t row = bm + (wr << 6) + (m << 4) + l15;
#pragma unroll
    for (int n = 0; n < 4; ++n) {
      const int col0 = bn + (wc << 6) + (n << 4) + (lk << 2);
      if (EPI == 0) epi_relu_h(acc[m][n], bias, col0, Hout, row, N);
      else          epi_head(acc[m][n], bias, col0, row, out_pi, out_mu, out_tril);
    }
  }
}

// -------- 8-phase counted-vmcnt GEMM (rounds 4-11 verified) — L1/L2 --------

template<int NH, int M_rep>
__device__ __forceinline__ void mfma_phase(const half8* af, const half8* bf,
                                           f32x4 (*acc)[4]) {
  __builtin_amdgcn_s_setprio(1);
#pragma unroll
  for (int m = 0; m < M_rep; ++m) {
    acc[m][NH * 2 + 0] = __builtin_amdgcn_mfma_f32_16x16x32_f16(bf[0], af[m], acc[m][NH * 2 + 0], 0, 0, 0);
    acc[m][NH * 2 + 1] = __builtin_amdgcn_mfma_f32_16x16x32_f16(bf[1], af[m], acc[m][NH * 2 + 1], 0, 0, 0);
  }
  __builtin_amdgcn_s_setprio(0);
}

template<int BM, int BN>
__global__ __launch_bounds__(512) void k_gemm8p(
    const unsigned short* __restrict__ A,
    const unsigned short* __restrict__ Bt,
    int Kd, int N, int nNb,
    const float* __restrict__ bias,
    unsigned short* __restrict__ Hout)
{
  constexpr int M_rep = BM / 32;
  constexpr int A_LD  = BM / 128;
  constexpr int B_LD  = BN / 128;
  constexpr int WN    = A_LD + B_LD;

  __shared__ unsigned short Ald[2][2][BM * 32];
  __shared__ unsigned short Bld[2][2][BN * 32];

  const int tid  = threadIdx.x;
  const int lane = tid & 63;
  const int wid  = tid >> 6;
  const int wm   = wid >> 2;
  const int wn   = wid & 3;
  const int l15  = lane & 15;
  const int lk   = lane >> 4;

  const int cpx = gridDim.x >> 3;
  const int bid = blockIdx.x;
  const int swz = (bid & 7) * cpx + (bid >> 3);
  const int bm  = (swz / nNb) * BM;
  const int bn  = (swz % nNb) * BN;

  const unsigned short* aBase = A  + (size_t)bm * Kd;
  const unsigned short* bBase = Bt + (size_t)bn * Kd;

  f32x4 acc[M_rep][4] = {};

  const int xo   = ((lk ^ ((l15 >> 1) & 3)) << 3);
  const int rowA = wm * (BM / 2) + l15;
  const int colB = wn * 64 + l15;

  auto stageA = [&](int bb, int h, int k0) {
#pragma unroll
    for (int i = 0; i < A_LD; ++i) {
      const int cbase = (wid << 6) + (i << 9);
      const int c_    = cbase + lane;
      const int row   = c_ >> 2;
      const int sc    = (((c_ & 3) ^ ((c_ >> 3) & 3)) << 3);
      __builtin_amdgcn_global_load_lds(
          (const __attribute__((address_space(1))) void*)(aBase + (size_t)row * Kd + k0 + h * 32 + sc),
          (__attribute__((address_space(3))) void*)(&Ald[bb][h][(size_t)cbase << 3]),
          16, 0, 0);
    }
  };
  auto stageB = [&](int bb, int h, int k0) {
#pragma unroll
    for (int i = 0; i < B_LD; ++i) {
      const int cbase = (wid << 6) + (i << 9);
      const int c_    = cbase + lane;
      const int row   = c_ >> 2;
      const int sc    = (((c_ & 3) ^ ((c_ >> 3) & 3)) << 3);
      __builtin_amdgcn_global_load_lds(
          (const __attribute__((address_space(1))) void*)(bBase + (size_t)row * Kd + k0 + h * 32 + sc),
          (__attribute__((address_space(3))) void*)(&Bld[bb][h][(size_t)cbase << 3]),
          16, 0, 0);
    }
  };

#define RD_A(kk)                                                                 \
  {                                                                              \
    _Pragma("unroll")                                                            \
    for (int m = 0; m < M_rep; ++m)                                              \
      af[m] = *(const half8*)&Ald[cur][kk][(size_t)(rowA + m * 16) * 32 + xo];   \
  }
#define RD_B(kk, nh)                                                             \
  {                                                                              \
    _Pragma("unroll")                                                            \
    for (int n2 = 0; n2 < 2; ++n2)                                               \
      bf[n2] = *(const half8*)&Bld[cur][kk][(size_t)(colB + ((nh) * 2 + n2) * 16) * 32 + xo]; \
  }

  const int nk = Kd >> 6;
  stageA(0, 0, 0); stageB(0, 0, 0); stageA(0, 1, 0); stageB(0, 1, 0);
  vmw<WN>();
  barrier_raw();

  int cur = 0;
  for (int kt = 0; kt < nk; ++kt) {
    const bool pre = (kt + 1 < nk);
    const int  k0n = (kt + 1) << 6;
    half8 af[M_rep], bf[2];

    RD_A(0); RD_B(0, 0);
    if (pre) stageA(cur ^ 1, 0, k0n);
    barrier_raw(); lgkm0();
    mfma_phase<0, M_rep>(af, bf, acc);
    barrier_raw();

    RD_B(0, 1);
    if (pre) stageB(cur ^ 1, 0, k0n);
    barrier_raw(); lgkm0();
    mfma_phase<1, M_rep>(af, bf, acc);
    if (pre) vmw<WN>(); else vmw<0>();
    barrier_raw();

    RD_A(1); RD_B(1, 0);
    if (pre) stageA(cur ^ 1, 1, k0n);
    barrier_raw(); lgkm0();
    mfma_phase<0, M_rep>(af, bf, acc);
    barrier_raw();

    RD_B(1, 1);
    if (pre) stageB(cur ^ 1, 1, k0n);
    barrier_raw(); lgkm0();
    mfma_phase<1, M_rep>(af, bf, acc);
    if (pre) vmw<WN>();
    barrier_raw();

    cur ^= 1;
  }
#undef RD_A
#undef RD_B

#pragma unroll
  for (int m = 0; m < M_rep; ++m) {
    const size_t row = bm + wm * (BM / 2) + (m << 4) + l15;
#pragma unroll
    for (int n = 0; n < 4; ++n) {
      const int col0 = bn + wn * 64 + (n << 4) + (lk << 2);
      epi_relu_h(acc[m][n], bias, col0, Hout, row, N);
    }
  }
}

// ---------------- launch ----------------

extern "C" void kernel_launch(void* const* d_in, const int* in_sizes, int n_in,
                              void* d_out, int out_size, void* d_ws, size_t ws_size,
                              hipStream_t stream)
{
  const float* x   = (const float*)d_in[0];
  const float* W0  = (const float*)d_in[1];
  const float* b0  = (const float*)d_in[2];
  const float* W1  = (const float*)d_in[3];
  const float* b1  = (const float*)d_in[4];
  const float* W2  = (const float*)d_in[5];
  const float* b2  = (const float*)d_in[6];
  const float* Wpi = (const float*)d_in[7];
  const float* bpi = (const float*)d_in[8];
  const float* Wmu = (const float*)d_in[9];
  const float* bmu = (const float*)d_in[10];
  const float* Wt  = (const float*)d_in[11];
  const float* bt  = (const float*)d_in[12];

  char* ws = (char*)d_ws;
  unsigned short* h0  = (unsigned short*)(ws + 8388608);   // 33,554,432 B
  unsigned short* h1  = (unsigned short*)(ws + 41943040);  // 33,554,432 B
  unsigned short* h2  = (unsigned short*)(ws + 8388608);   // 16,777,216 B (aliases h0 — dead by then)
  unsigned short* w0b = (unsigned short*)(ws + 75497472);  //    524,288 B [1024][256]
  unsigned short* w1b = (unsigned short*)(ws + 76021760);  //  2,097,152 B [1024][1024]
  unsigned short* w2b = (unsigned short*)(ws + 78118912);  //  1,048,576 B [512][1024]
  unsigned short* whd = (unsigned short*)(ws + 79167488);  //  2,359,296 B [2304][512]
  float*          bhd = (float*)         (ws + 81526784);  //      9,216 B [2304]

  float* out_pi   = (float*)d_out;                // 131072
  float* out_mu   = (float*)d_out + 131072;       // 2097152
  float* out_tril = (float*)d_out + 2228224;      // 33554432

  // prep (x conversion kernel deleted — fused into L0)
  k_transpose_f16<<<128, 256, 0, stream>>>(W0, w0b, 256, 1024);
  k_transpose_f16<<<512, 256, 0, stream>>>(W1, w1b, 1024, 1024);
  k_transpose_f16<<<256, 256, 0, stream>>>(W2, w2b, 1024, 512);
  k_build_head<<<576, 256, 0, stream>>>(Wmu, Wt, Wpi, bmu, bt, bpi, whd, bhd);

  // L0: reads x f32 directly, converts during staging (T14 split), 1024 blocks
  k_gemm_l0<<<1024, 256, 0, stream>>>(x, w0b, b0, h0);
  // L1/L2: K=1024 -> 256-class 8-phase, 256 blocks (1/CU exact)
  k_gemm8p<256, 256><<<256, 512, 0, stream>>>(h0, w1b, 1024, 1024, 4, b1, h1);
  k_gemm8p<128, 256><<<256, 512, 0, stream>>>(h1, w2b, 1024, 512, 2, b2, h2);
  // head: N=2304 (mu|tril-unpacked|pi|pad), 3-buffer counted-vmcnt, 2304 blocks
  k_gemm3b<1><<<2304, 256, 0, stream>>>(h2, whd, 512, 2304, 18, bhd, nullptr,
                                        out_pi, out_mu, out_tril);
}